// Round 6
// baseline (236.732 us; speedup 1.0000x reference)
//
#include <hip/hip_runtime.h>
#include <hip/hip_bf16.h>
#include <hip/hip_fp16.h>
#include <math.h>

// Problem constants (match reference)
#define NN 50000      // nodes (< 65536 -> u16 CSR entries); NN/16 = 3125 exactly
#define NE 800000     // edges (before self loops)
#define DD 128        // feature dim
#define NG 512        // graphs
#define NSA 0.2f      // attention leaky_relu slope
#define NSB 0.01f     // activation leaky_relu slope
#define EPS 1e-16f
#define CAP 61        // real-edge slots per node (max observed degree ~38, Poisson(16))

typedef _Float16 half8 __attribute__((ext_vector_type(8)));
typedef float    floatx4 __attribute__((ext_vector_type(4)));

// ---------------- init: zero dense counters + d_out, convert W0..W2 to fp16 ---------
__global__ void init_kernel(unsigned int* __restrict__ cnt, float* __restrict__ out,
                            const float* __restrict__ W0, const float* __restrict__ W1,
                            const float* __restrict__ W2, __half* __restrict__ w16) {
    int i = blockIdx.x * 256 + threadIdx.x;
    if (i < NN) cnt[i] = 0u;
    if (i < NG * DD) out[i] = 0.f;
    if (i < 3 * DD * DD) {
        int layer = i / (DD * DD), idx = i % (DD * DD);
        const float* Ws = (layer == 0) ? W0 : (layer == 1) ? W1 : W2;
        w16[i] = __float2half(Ws[idx]);
    }
}

// ---------------- MFMA GEMM body (layer 0 only): 64x128 tile, 4 waves ---------------
#define BM 64
__device__ __forceinline__ void gemm_mfma_body(
        const float* __restrict__ X, const __half* __restrict__ W16,
        const float* __restrict__ a_src, const float* __restrict__ a_dst,
        __half* __restrict__ H16, float* __restrict__ as_, float* __restrict__ ad_,
        int row0, __half (*tile)[136]) {
    int t    = threadIdx.x;
    int wave = t >> 6;
    int lane = t & 63;
    int quad = lane >> 4;
    int mrow = lane & 15;
    int gl = min(row0 + wave * 16 + mrow, NN - 1);

    half8 afrag[4];
    #pragma unroll
    for (int kc = 0; kc < 4; ++kc) {
        int k = kc * 32 + quad * 8;
        float4 u0 = *(const float4*)&X[(size_t)gl * DD + k];
        float4 u1 = *(const float4*)&X[(size_t)gl * DD + k + 4];
        half8 a;
        a[0] = (_Float16)u0.x; a[1] = (_Float16)u0.y;
        a[2] = (_Float16)u0.z; a[3] = (_Float16)u0.w;
        a[4] = (_Float16)u1.x; a[5] = (_Float16)u1.y;
        a[6] = (_Float16)u1.z; a[7] = (_Float16)u1.w;
        afrag[kc] = a;
    }

    floatx4 acc[8] = {};
    #pragma unroll
    for (int ct = 0; ct < 8; ++ct) {
        #pragma unroll
        for (int kc = 0; kc < 4; ++kc) {
            half8 b = *(const half8*)&W16[(size_t)(ct * 16 + mrow) * DD + kc * 32 + quad * 8];
            acc[ct] = __builtin_amdgcn_mfma_f32_16x16x32_f16(afrag[kc], b, acc[ct], 0, 0, 0);
        }
    }
    #pragma unroll
    for (int ct = 0; ct < 8; ++ct) {
        #pragma unroll
        for (int reg = 0; reg < 4; ++reg)
            tile[wave * 16 + quad * 4 + reg][ct * 16 + mrow] = __float2half(acc[ct][reg]);
    }
    __syncthreads();

    int tx = t & 15;
    int ty = t >> 4;
    float asv[8], adv[8];
    #pragma unroll
    for (int c = 0; c < 8; ++c) {
        asv[c] = a_src[tx * 8 + c];
        adv[c] = a_dst[tx * 8 + c];
    }
    #pragma unroll
    for (int r = 0; r < 4; ++r) {
        int row = ty * 4 + r;
        int gr = row0 + row;
        float4 raw = *(const float4*)&tile[row][tx * 8];
        const __half2* q = (const __half2*)&raw;
        float2 c01 = __half22float2(q[0]);
        float2 c23 = __half22float2(q[1]);
        float2 c45 = __half22float2(q[2]);
        float2 c67 = __half22float2(q[3]);
        float hv[8] = {c01.x, c01.y, c23.x, c23.y, c45.x, c45.y, c67.x, c67.y};
        float ps = 0.f, pd = 0.f;
        #pragma unroll
        for (int c = 0; c < 8; ++c) {
            ps += hv[c] * asv[c];
            pd += hv[c] * adv[c];
        }
        #pragma unroll
        for (int off = 8; off >= 1; off >>= 1) {
            ps += __shfl_xor(ps, off);
            pd += __shfl_xor(pd, off);
        }
        if (gr < NN) {
            if (tx == 0) { as_[gr] = ps; ad_[gr] = pd; }
            *(float4*)&H16[(size_t)gr * DD + tx * 8] = raw;
        }
    }
}

// ---------------- FAT kernel: gemm + scatter; scatter = 8 edges/thread --------------
// 1173 blocks: first 782 alternate gemm/scatter (391 scatter blocks interleaved so
// both streams start immediately), remaining 391 are gemm. 8 independent atomic
// chains per scatter thread (2x the MLP of the 4/thread version).
__global__ __launch_bounds__(256, 8) void fat_kernel(
        const float* __restrict__ X, const __half* __restrict__ W16,
        const float* __restrict__ a_src, const float* __restrict__ a_dst,
        __half* __restrict__ H16, float* __restrict__ as_, float* __restrict__ ad_,
        const int* __restrict__ esrc, const int* __restrict__ edst,
        unsigned int* __restrict__ cnt, unsigned short* __restrict__ slots) {
    __shared__ __half tile[BM][136];
    int bx = blockIdx.x;
    if ((bx < 782) && (bx & 1)) {
        int i = (bx >> 1) * 256 + threadIdx.x;      // scatter idx in [0, 100096)
        if (i < NE / 8) {
            int4 sa = ((const int4*)esrc)[i * 2];
            int4 sb = ((const int4*)esrc)[i * 2 + 1];
            int4 da = ((const int4*)edst)[i * 2];
            int4 db = ((const int4*)edst)[i * 2 + 1];
            int k0 = (int)atomicAdd(&cnt[da.x], 1u);
            int k1 = (int)atomicAdd(&cnt[da.y], 1u);
            int k2 = (int)atomicAdd(&cnt[da.z], 1u);
            int k3 = (int)atomicAdd(&cnt[da.w], 1u);
            int k4 = (int)atomicAdd(&cnt[db.x], 1u);
            int k5 = (int)atomicAdd(&cnt[db.y], 1u);
            int k6 = (int)atomicAdd(&cnt[db.z], 1u);
            int k7 = (int)atomicAdd(&cnt[db.w], 1u);
            if (k0 < CAP) slots[((size_t)da.x << 6) + k0] = (unsigned short)sa.x;
            if (k1 < CAP) slots[((size_t)da.y << 6) + k1] = (unsigned short)sa.y;
            if (k2 < CAP) slots[((size_t)da.z << 6) + k2] = (unsigned short)sa.z;
            if (k3 < CAP) slots[((size_t)da.w << 6) + k3] = (unsigned short)sa.w;
            if (k4 < CAP) slots[((size_t)db.x << 6) + k4] = (unsigned short)sb.x;
            if (k5 < CAP) slots[((size_t)db.y << 6) + k5] = (unsigned short)sb.y;
            if (k6 < CAP) slots[((size_t)db.z << 6) + k6] = (unsigned short)sb.z;
            if (k7 < CAP) slots[((size_t)db.w << 6) + k7] = (unsigned short)sb.w;
        }
        return;
    }
    int gb = (bx < 782) ? (bx >> 1) : (bx - 391);   // 0..390 | 391..781
    gemm_mfma_body(X, W16, a_src, a_dst, H16, as_, ad_, gb * BM, tile);
}

__device__ inline void fma_h8(float4& a0, float4& a1, float p, const float4& raw) {
    const __half2* q = (const __half2*)&raw;
    float2 c;
    c = __half22float2(q[0]); a0.x += p * c.x; a0.y += p * c.y;
    c = __half22float2(q[1]); a0.z += p * c.x; a0.w += p * c.y;
    c = __half22float2(q[2]); a1.x += p * c.x; a1.y += p * c.y;
    c = __half22float2(q[3]); a1.z += p * c.x; a1.w += p * c.y;
}

// load 8 H-rows (compile-time chunk cc) into the single working buffer
#define LDCH(cc) do {                                                         \
    int4 _i0 = *(const int4*)&srow[(cc) * 8];                                 \
    int4 _i1 = *(const int4*)&srow[(cc) * 8 + 4];                             \
    R0 = H4[(size_t)_i0.x * 16 + d];                                          \
    R1 = H4[(size_t)_i0.y * 16 + d];                                          \
    R2 = H4[(size_t)_i0.z * 16 + d];                                          \
    R3 = H4[(size_t)_i0.w * 16 + d];                                          \
    R4 = H4[(size_t)_i1.x * 16 + d];                                          \
    R5 = H4[(size_t)_i1.y * 16 + d];                                          \
    R6 = H4[(size_t)_i1.z * 16 + d];                                          \
    R7 = H4[(size_t)_i1.w * 16 + d];                                          \
} while (0)

#define EAT(cc) do {                                                          \
    float4 _q0 = *(const float4*)&prow[(cc) * 8];                             \
    float4 _q1 = *(const float4*)&prow[(cc) * 8 + 4];                         \
    fma_h8(a0, a1, _q0.x, R0);                                                \
    fma_h8(a0, a1, _q0.y, R1);                                                \
    fma_h8(a0, a1, _q0.z, R2);                                                \
    fma_h8(a0, a1, _q0.w, R3);                                                \
    fma_h8(a0, a1, _q1.x, R4);                                                \
    fma_h8(a0, a1, _q1.y, R5);                                                \
    fma_h8(a0, a1, _q1.z, R6);                                                \
    fma_h8(a0, a1, _q1.w, R7);                                                \
} while (0)

// ---- BATCHED agg, 4 nodes/wave; 16-lane group per node (R4 structure) --------------
// At 24 waves/CU the TLP hides gather latency (R5's deeper pipeline was null);
// keep the two proven pieces: chunk-0 hoist above the softmax + group-parallel
// softmax. Tail slots hold the self node index with e=-1e30 -> p=0: no masks.
__device__ __forceinline__ void agg_batch4(
        int row0, int wid, int lane,
        const __half* __restrict__ H16, const float* __restrict__ as_,
        const float* __restrict__ ad_, const unsigned int* __restrict__ cnt,
        const unsigned short* __restrict__ slots,
        float (*p_sh)[4][64], int (*s_sh)[4][64], __half (*ytile)[136],
        int apply_lrelu) {
    int nodes[4], deg[4];
    float adn[4];

    // ---- phase 1a: metadata, batched ----
    int cv[4];
    #pragma unroll
    for (int it = 0; it < 4; ++it) {
        nodes[it] = row0 + it * 4 + wid;
        cv[it] = (int)cnt[nodes[it]];
    }
    int sl[4];
    #pragma unroll
    for (int it = 0; it < 4; ++it)
        sl[it] = (int)slots[((size_t)nodes[it] << 6) + lane];
    #pragma unroll
    for (int it = 0; it < 4; ++it) adn[it] = ad_[nodes[it]];
    int svv[4];
    #pragma unroll
    for (int it = 0; it < 4; ++it) {
        int dr = min(cv[it], CAP);
        deg[it] = dr + 1;
        svv[it] = (lane < dr) ? sl[it] : nodes[it];
        s_sh[wid][it][lane] = svv[it];
    }
    float av[4];
    #pragma unroll
    for (int it = 0; it < 4; ++it) av[it] = as_[svv[it]];   // random 4B gathers, in flight
    __builtin_amdgcn_wave_barrier();   // s_sh valid wave-wide

    // ---- group setup ----
    int g = lane >> 4;
    int d = lane & 15;
    int dg = (g == 0) ? deg[0] : (g == 1) ? deg[1] : (g == 2) ? deg[2] : deg[3];
    const int*    srow = s_sh[wid][g];
    float*        prow = p_sh[wid][g];
    const float4* H4   = (const float4*)H16;
    int nch = (dg + 7) >> 3;           // 1..8

    // ---- early-issue chunk 0: 8 rows in flight across the softmax ----
    float4 R0, R1, R2, R3, R4, R5, R6, R7;
    LDCH(0);
    __builtin_amdgcn_sched_barrier(0);  // pin the loads above the softmax

    // ---- e -> LDS (waits only on av/adn) ----
    #pragma unroll
    for (int it = 0; it < 4; ++it) {
        float e = -1e30f;
        if (lane < deg[it]) {
            float ev = av[it] + adn[it];
            e = (ev > 0.f) ? ev : NSA * ev;
        }
        p_sh[wid][it][lane] = e;
    }
    __builtin_amdgcn_wave_barrier();

    // ---- group-parallel softmax over own node's 64 slots ----
    float4 ev4 = *(const float4*)&prow[d * 4];
    float m = fmaxf(fmaxf(ev4.x, ev4.y), fmaxf(ev4.z, ev4.w));
    #pragma unroll
    for (int off = 8; off >= 1; off >>= 1) m = fmaxf(m, __shfl_xor(m, off));
    float4 pv;
    pv.x = __expf(ev4.x - m);          // tail e=-1e30 -> 0
    pv.y = __expf(ev4.y - m);
    pv.z = __expf(ev4.z - m);
    pv.w = __expf(ev4.w - m);
    *(float4*)&prow[d * 4] = pv;
    float lsum = pv.x + pv.y + pv.z + pv.w;
    #pragma unroll
    for (int off = 8; off >= 1; off >>= 1) lsum += __shfl_xor(lsum, off);
    __builtin_amdgcn_wave_barrier();   // p values valid group-wide

    // ---- phase 2: consume chunk, reload in place ----
    float4 a0 = {0, 0, 0, 0}, a1 = {0, 0, 0, 0};
    int c = 0;
    while (true) {
        EAT(c);
        if (++c >= nch) break;
        LDCH(c);
    }

    float inv = 1.f / (lsum + EPS);
    float4 o0, o1;
    o0.x = a0.x * inv; o0.y = a0.y * inv; o0.z = a0.z * inv; o0.w = a0.w * inv;
    o1.x = a1.x * inv; o1.y = a1.y * inv; o1.z = a1.z * inv; o1.w = a1.w * inv;
    if (apply_lrelu) {
        o0.x = (o0.x > 0.f) ? o0.x : NSB * o0.x;
        o0.y = (o0.y > 0.f) ? o0.y : NSB * o0.y;
        o0.z = (o0.z > 0.f) ? o0.z : NSB * o0.z;
        o0.w = (o0.w > 0.f) ? o0.w : NSB * o0.w;
        o1.x = (o1.x > 0.f) ? o1.x : NSB * o1.x;
        o1.y = (o1.y > 0.f) ? o1.y : NSB * o1.y;
        o1.z = (o1.z > 0.f) ? o1.z : NSB * o1.z;
        o1.w = (o1.w > 0.f) ? o1.w : NSB * o1.w;
    }
    __half2 hh[4];
    hh[0] = __floats2half2_rn(o0.x, o0.y);
    hh[1] = __floats2half2_rn(o0.z, o0.w);
    hh[2] = __floats2half2_rn(o1.x, o1.y);
    hh[3] = __floats2half2_rn(o1.z, o1.w);
    *(float4*)&ytile[g * 4 + wid][d * 8] = *(float4*)hh;
}

// ---------------- FUSED agg+gemm: 16 nodes/block; agg -> LDS -> 16x128 MFMA ----------
__global__ __launch_bounds__(256, 6) void agg_gemm_kernel(
        const __half* __restrict__ H_in, const float* __restrict__ as_in,
        const float* __restrict__ ad_in, const unsigned int* __restrict__ cnt,
        const unsigned short* __restrict__ slots,
        const __half* __restrict__ W16, const float* __restrict__ a_src,
        const float* __restrict__ a_dst, __half* __restrict__ H_out,
        float* __restrict__ as_out, float* __restrict__ ad_out, int apply_lrelu) {
    __shared__ float  p_sh[4][4][64];
    __shared__ int    s_sh[4][4][64];
    __shared__ __half ytile[16][136];   // agg rows (A), later reused for C
    int t = threadIdx.x;
    int wid = t >> 6, lane = t & 63;
    int row0 = blockIdx.x * 16;

    agg_batch4(row0, wid, lane, H_in, as_in, ad_in, cnt, slots, p_sh, s_sh, ytile,
               apply_lrelu);
    __syncthreads();   // ytile complete

    int quad = lane >> 4, mrow = lane & 15;
    half8 afrag[4];
    #pragma unroll
    for (int kc = 0; kc < 4; ++kc)
        afrag[kc] = *(const half8*)&ytile[mrow][kc * 32 + quad * 8];
    __syncthreads();   // all A reads done; ytile reusable for C

    floatx4 acc[2] = {};
    #pragma unroll
    for (int cc = 0; cc < 2; ++cc) {
        int ct = wid * 2 + cc;
        #pragma unroll
        for (int kc = 0; kc < 4; ++kc) {
            half8 b = *(const half8*)&W16[(size_t)(ct * 16 + mrow) * DD + kc * 32 + quad * 8];
            acc[cc] = __builtin_amdgcn_mfma_f32_16x16x32_f16(afrag[kc], b, acc[cc], 0, 0, 0);
        }
    }
    #pragma unroll
    for (int cc = 0; cc < 2; ++cc) {
        int ct = wid * 2 + cc;
        #pragma unroll
        for (int reg = 0; reg < 4; ++reg)
            ytile[quad * 4 + reg][ct * 16 + mrow] = __float2half(acc[cc][reg]);
    }
    __syncthreads();

    int row = t >> 4, cg = t & 15;
    int gr = row0 + row;
    float4 raw = *(const float4*)&ytile[row][cg * 8];
    const __half2* q = (const __half2*)&raw;
    float2 c01 = __half22float2(q[0]);
    float2 c23 = __half22float2(q[1]);
    float2 c45 = __half22float2(q[2]);
    float2 c67 = __half22float2(q[3]);
    float hv[8] = {c01.x, c01.y, c23.x, c23.y, c45.x, c45.y, c67.x, c67.y};
    float ps = 0.f, pd = 0.f;
    #pragma unroll
    for (int c = 0; c < 8; ++c) {
        ps += hv[c] * a_src[cg * 8 + c];
        pd += hv[c] * a_dst[cg * 8 + c];
    }
    #pragma unroll
    for (int off = 8; off >= 1; off >>= 1) {
        ps += __shfl_xor(ps, off);
        pd += __shfl_xor(pd, off);
    }
    if (cg == 0) { as_out[gr] = ps; ad_out[gr] = pd; }
    *(float4*)&H_out[(size_t)gr * DD + cg * 8] = raw;
}

// ---------------- FUSED layer-2 agg + global_add_pool: 16 nodes/block ---------------
__global__ __launch_bounds__(256, 6) void agg_pool_kernel(
        const __half* __restrict__ H_in, const float* __restrict__ as_in,
        const float* __restrict__ ad_in, const unsigned int* __restrict__ cnt,
        const unsigned short* __restrict__ slots,
        const int* __restrict__ batch, float* __restrict__ out) {
    __shared__ float  p_sh[4][4][64];
    __shared__ int    s_sh[4][4][64];
    __shared__ __half ytile[16][136];
    int t = threadIdx.x;
    int wid = t >> 6, lane = t & 63;
    int row0 = blockIdx.x * 16;

    agg_batch4(row0, wid, lane, H_in, as_in, ad_in, cnt, slots, p_sh, s_sh, ytile, 0);
    __syncthreads();   // ytile complete

    // pool phase: rh = row half (0: rows 0-7, 1: rows 8-15), d = dim 0..127
    int rh = t >> 7;
    int d  = t & 127;
    int r0 = rh * 8;
    float acc = 0.f;
    int g = batch[row0 + r0];
    #pragma unroll
    for (int r = 0; r < 8; ++r) {
        int n = row0 + r0 + r;
        int gn = batch[n];
        if (gn != g) {
            atomicAdd(&out[(size_t)g * DD + d], acc);
            acc = 0.f;
            g = gn;
        }
        acc += __half2float(ytile[r0 + r][d]);
    }
    atomicAdd(&out[(size_t)g * DD + d], acc);
}

extern "C" void kernel_launch(void* const* d_in, const int* in_sizes, int n_in,
                              void* d_out, int out_size, void* d_ws, size_t ws_size,
                              hipStream_t stream) {
    const float* x      = (const float*)d_in[0];
    const int*   ei     = (const int*)d_in[1];
    const int*   batch  = (const int*)d_in[2];
    const int*   src    = ei;
    const int*   dst    = ei + NE;
    float* out = (float*)d_out;

    size_t off = 0;
    auto carve = [&](size_t bytes) {
        void* p = (char*)d_ws + off;
        off += (bytes + 255) & ~(size_t)255;
        return p;
    };
    __half* h16a  = (__half*)carve((size_t)NN * DD * 2);      // ping
    __half* h16b  = (__half*)carve((size_t)NN * DD * 2);      // pong
    float*  as_a  = (float*)carve((size_t)NN * 4);
    float*  ad_a  = (float*)carve((size_t)NN * 4);
    float*  as_b  = (float*)carve((size_t)NN * 4);
    float*  ad_b  = (float*)carve((size_t)NN * 4);
    unsigned int*   cnt   = (unsigned int*)carve((size_t)NN * 4);        // dense
    unsigned short* slots = (unsigned short*)carve((size_t)NN * 64 * 2); // store-only
    __half* w16   = (__half*)carve((size_t)3 * DD * DD * 2);

    const int fat_blocks  = 1173;                    // 782 gemm + 391 scatter(8/thr)
    const int fuse_blocks = NN / 16;                 // 3125
    const int init_blocks = (NG * DD + 255) / 256;   // 256 (covers NN and 3*DD*DD)

    const float* W0  = (const float*)d_in[3];
    const float* av0 = (const float*)d_in[4];
    const float* ad0 = (const float*)d_in[5];
    const float* av1 = (const float*)d_in[7];
    const float* ad1 = (const float*)d_in[8];
    const float* av2 = (const float*)d_in[10];
    const float* ad2 = (const float*)d_in[11];

    // ---- init + (gemm0-MFMA || scatter, interleaved) ----
    init_kernel<<<init_blocks, 256, 0, stream>>>(cnt, out, W0,
                                                 (const float*)d_in[6],
                                                 (const float*)d_in[9], w16);
    fat_kernel<<<fat_blocks, 256, 0, stream>>>(
        x, w16, av0, ad0, h16a, as_a, ad_a, src, dst, cnt, slots);

    // ---- fused agg0+gemm1 (hA->hB), fused agg1+lrelu+gemm2 (hB->hA) ----
    agg_gemm_kernel<<<fuse_blocks, 256, 0, stream>>>(
        h16a, as_a, ad_a, cnt, slots, w16 + (size_t)1 * DD * DD, av1, ad1,
        h16b, as_b, ad_b, 0);
    agg_gemm_kernel<<<fuse_blocks, 256, 0, stream>>>(
        h16b, as_b, ad_b, cnt, slots, w16 + (size_t)2 * DD * DD, av2, ad2,
        h16a, as_a, ad_a, 1);

    // ---- fused layer-2 agg + pool ----
    agg_pool_kernel<<<fuse_blocks, 256, 0, stream>>>(h16a, as_a, ad_a, cnt, slots,
                                                     batch, out);
}

// Round 7
// 227.297 us; speedup vs baseline: 1.0415x; 1.0415x over previous
//
#include <hip/hip_runtime.h>
#include <hip/hip_bf16.h>
#include <hip/hip_fp16.h>
#include <math.h>

// Problem constants (match reference)
#define NN 50000      // nodes (< 65536 -> u16 CSR entries); NN/16 = 3125 exactly
#define NE 800000     // edges (before self loops)
#define DD 128        // feature dim
#define NG 512        // graphs
#define NSA 0.2f      // attention leaky_relu slope
#define NSB 0.01f     // activation leaky_relu slope
#define EPS 1e-16f
#define CAP 61        // real-edge slots per node (max observed degree ~38, Poisson(16))

typedef _Float16 half8 __attribute__((ext_vector_type(8)));
typedef float    floatx4 __attribute__((ext_vector_type(4)));

// ---------------- init: zero dense counters + d_out, convert W0..W2 to fp16 ---------
__global__ void init_kernel(unsigned int* __restrict__ cnt, float* __restrict__ out,
                            const float* __restrict__ W0, const float* __restrict__ W1,
                            const float* __restrict__ W2, __half* __restrict__ w16) {
    int i = blockIdx.x * 256 + threadIdx.x;
    if (i < NN) cnt[i] = 0u;
    if (i < NG * DD) out[i] = 0.f;
    if (i < 3 * DD * DD) {
        int layer = i / (DD * DD), idx = i % (DD * DD);
        const float* Ws = (layer == 0) ? W0 : (layer == 1) ? W1 : W2;
        w16[i] = __float2half(Ws[idx]);
    }
}

// ---------------- MFMA GEMM body (layer 0 only): 64x128 tile, 4 waves ---------------
#define BM 64
__device__ __forceinline__ void gemm_mfma_body(
        const float* __restrict__ X, const __half* __restrict__ W16,
        const float* __restrict__ a_src, const float* __restrict__ a_dst,
        __half* __restrict__ H16, float* __restrict__ as_, float* __restrict__ ad_,
        int row0, __half (*tile)[136]) {
    int t    = threadIdx.x;
    int wave = t >> 6;
    int lane = t & 63;
    int quad = lane >> 4;
    int mrow = lane & 15;
    int gl = min(row0 + wave * 16 + mrow, NN - 1);

    half8 afrag[4];
    #pragma unroll
    for (int kc = 0; kc < 4; ++kc) {
        int k = kc * 32 + quad * 8;
        float4 u0 = *(const float4*)&X[(size_t)gl * DD + k];
        float4 u1 = *(const float4*)&X[(size_t)gl * DD + k + 4];
        half8 a;
        a[0] = (_Float16)u0.x; a[1] = (_Float16)u0.y;
        a[2] = (_Float16)u0.z; a[3] = (_Float16)u0.w;
        a[4] = (_Float16)u1.x; a[5] = (_Float16)u1.y;
        a[6] = (_Float16)u1.z; a[7] = (_Float16)u1.w;
        afrag[kc] = a;
    }

    floatx4 acc[8] = {};
    #pragma unroll
    for (int ct = 0; ct < 8; ++ct) {
        #pragma unroll
        for (int kc = 0; kc < 4; ++kc) {
            half8 b = *(const half8*)&W16[(size_t)(ct * 16 + mrow) * DD + kc * 32 + quad * 8];
            acc[ct] = __builtin_amdgcn_mfma_f32_16x16x32_f16(afrag[kc], b, acc[ct], 0, 0, 0);
        }
    }
    #pragma unroll
    for (int ct = 0; ct < 8; ++ct) {
        #pragma unroll
        for (int reg = 0; reg < 4; ++reg)
            tile[wave * 16 + quad * 4 + reg][ct * 16 + mrow] = __float2half(acc[ct][reg]);
    }
    __syncthreads();

    int tx = t & 15;
    int ty = t >> 4;
    float asv[8], adv[8];
    #pragma unroll
    for (int c = 0; c < 8; ++c) {
        asv[c] = a_src[tx * 8 + c];
        adv[c] = a_dst[tx * 8 + c];
    }
    #pragma unroll
    for (int r = 0; r < 4; ++r) {
        int row = ty * 4 + r;
        int gr = row0 + row;
        float4 raw = *(const float4*)&tile[row][tx * 8];
        const __half2* q = (const __half2*)&raw;
        float2 c01 = __half22float2(q[0]);
        float2 c23 = __half22float2(q[1]);
        float2 c45 = __half22float2(q[2]);
        float2 c67 = __half22float2(q[3]);
        float hv[8] = {c01.x, c01.y, c23.x, c23.y, c45.x, c45.y, c67.x, c67.y};
        float ps = 0.f, pd = 0.f;
        #pragma unroll
        for (int c = 0; c < 8; ++c) {
            ps += hv[c] * asv[c];
            pd += hv[c] * adv[c];
        }
        #pragma unroll
        for (int off = 8; off >= 1; off >>= 1) {
            ps += __shfl_xor(ps, off);
            pd += __shfl_xor(pd, off);
        }
        if (gr < NN) {
            if (tx == 0) { as_[gr] = ps; ad_[gr] = pd; }
            *(float4*)&H16[(size_t)gr * DD + tx * 8] = raw;
        }
    }
}

// ---------------- FAT kernel: gemm/scatter interleaved 1:1 by blockIdx parity -------
// scatter: 4 edges/thread, 782 scatter blocks; counters dense (atomic-only array);
// slot stores go to a separate u16 array. 8 waves/EU keeps the atomic pipe fed.
// (8 edges/thread with 391 blocks measured SLOWER: fewer resident scatter waves.)
__global__ __launch_bounds__(256, 8) void fat_kernel(
        const float* __restrict__ X, const __half* __restrict__ W16,
        const float* __restrict__ a_src, const float* __restrict__ a_dst,
        __half* __restrict__ H16, float* __restrict__ as_, float* __restrict__ ad_,
        const int* __restrict__ esrc, const int* __restrict__ edst,
        unsigned int* __restrict__ cnt, unsigned short* __restrict__ slots) {
    __shared__ __half tile[BM][136];
    int bx = blockIdx.x;
    if (bx & 1) {
        int i = (bx >> 1) * 256 + threadIdx.x;
        if (i < NE / 4) {
            int4 s4 = ((const int4*)esrc)[i];
            int4 d4 = ((const int4*)edst)[i];
            int k0 = (int)atomicAdd(&cnt[d4.x], 1u);
            int k1 = (int)atomicAdd(&cnt[d4.y], 1u);
            int k2 = (int)atomicAdd(&cnt[d4.z], 1u);
            int k3 = (int)atomicAdd(&cnt[d4.w], 1u);
            if (k0 < CAP) slots[((size_t)d4.x << 6) + k0] = (unsigned short)s4.x;
            if (k1 < CAP) slots[((size_t)d4.y << 6) + k1] = (unsigned short)s4.y;
            if (k2 < CAP) slots[((size_t)d4.z << 6) + k2] = (unsigned short)s4.z;
            if (k3 < CAP) slots[((size_t)d4.w << 6) + k3] = (unsigned short)s4.w;
        }
        return;
    }
    gemm_mfma_body(X, W16, a_src, a_dst, H16, as_, ad_, (bx >> 1) * BM, tile);
}

__device__ inline void fma_h8(float4& a0, float4& a1, float p, const float4& raw) {
    const __half2* q = (const __half2*)&raw;
    float2 c;
    c = __half22float2(q[0]); a0.x += p * c.x; a0.y += p * c.y;
    c = __half22float2(q[1]); a0.z += p * c.x; a0.w += p * c.y;
    c = __half22float2(q[2]); a1.x += p * c.x; a1.y += p * c.y;
    c = __half22float2(q[3]); a1.z += p * c.x; a1.w += p * c.y;
}

// load 8 H-rows (chunk cc) for this lane's group into the single working buffer
#define LDCH(cc) do {                                                         \
    int4 _i0 = *(const int4*)&srow[(cc) * 8];                                 \
    int4 _i1 = *(const int4*)&srow[(cc) * 8 + 4];                             \
    R0 = H4[(size_t)_i0.x * 16 + d];                                          \
    R1 = H4[(size_t)_i0.y * 16 + d];                                          \
    R2 = H4[(size_t)_i0.z * 16 + d];                                          \
    R3 = H4[(size_t)_i0.w * 16 + d];                                          \
    R4 = H4[(size_t)_i1.x * 16 + d];                                          \
    R5 = H4[(size_t)_i1.y * 16 + d];                                          \
    R6 = H4[(size_t)_i1.z * 16 + d];                                          \
    R7 = H4[(size_t)_i1.w * 16 + d];                                          \
} while (0)

#define EAT(cc) do {                                                          \
    float4 _q0 = *(const float4*)&prow[(cc) * 8];                             \
    float4 _q1 = *(const float4*)&prow[(cc) * 8 + 4];                         \
    fma_h8(a0, a1, _q0.x, R0);                                                \
    fma_h8(a0, a1, _q0.y, R1);                                                \
    fma_h8(a0, a1, _q0.z, R2);                                                \
    fma_h8(a0, a1, _q0.w, R3);                                                \
    fma_h8(a0, a1, _q1.x, R4);                                                \
    fma_h8(a0, a1, _q1.y, R5);                                                \
    fma_h8(a0, a1, _q1.z, R6);                                                \
    fma_h8(a0, a1, _q1.w, R7);                                                \
} while (0)

// ---- BATCHED agg, 4 nodes/wave; 16-lane group per node -----------------------------
// Best-measured structure (R4): single 8-row register buffer, in-place reload,
// chunk-0 hoisted above the group-parallel softmax, LB(256,6) for TLP.
// Tail slots hold the self node index (valid rows) with e=-1e30 -> p=0: no masks.
__device__ __forceinline__ void agg_batch4(
        int row0, int wid, int lane,
        const __half* __restrict__ H16, const float* __restrict__ as_,
        const float* __restrict__ ad_, const unsigned int* __restrict__ cnt,
        const unsigned short* __restrict__ slots,
        float (*p_sh)[4][64], int (*s_sh)[4][64], __half (*ytile)[136],
        int apply_lrelu) {
    int nodes[4], deg[4];
    float adn[4];

    // ---- phase 1a: metadata, batched ----
    int cv[4];
    #pragma unroll
    for (int it = 0; it < 4; ++it) {
        nodes[it] = row0 + it * 4 + wid;
        cv[it] = (int)cnt[nodes[it]];
    }
    int sl[4];
    #pragma unroll
    for (int it = 0; it < 4; ++it)
        sl[it] = (int)slots[((size_t)nodes[it] << 6) + lane];
    #pragma unroll
    for (int it = 0; it < 4; ++it) adn[it] = ad_[nodes[it]];
    int svv[4];
    #pragma unroll
    for (int it = 0; it < 4; ++it) {
        int dr = min(cv[it], CAP);
        deg[it] = dr + 1;
        svv[it] = (lane < dr) ? sl[it] : nodes[it];
        s_sh[wid][it][lane] = svv[it];
    }
    float av[4];
    #pragma unroll
    for (int it = 0; it < 4; ++it) av[it] = as_[svv[it]];   // random 4B gathers, in flight
    __builtin_amdgcn_wave_barrier();   // s_sh valid wave-wide

    // ---- group setup ----
    int g = lane >> 4;
    int d = lane & 15;
    int dg = (g == 0) ? deg[0] : (g == 1) ? deg[1] : (g == 2) ? deg[2] : deg[3];
    const int*    srow = s_sh[wid][g];
    float*        prow = p_sh[wid][g];
    const float4* H4   = (const float4*)H16;
    int nch = (dg + 7) >> 3;           // 1..8

    // ---- early-issue chunk 0: 8 rows in flight across the softmax ----
    float4 R0, R1, R2, R3, R4, R5, R6, R7;
    LDCH(0);
    __builtin_amdgcn_sched_barrier(0);  // pin the loads above the softmax

    // ---- e -> LDS (waits only on av/adn) ----
    #pragma unroll
    for (int it = 0; it < 4; ++it) {
        float e = -1e30f;
        if (lane < deg[it]) {
            float ev = av[it] + adn[it];
            e = (ev > 0.f) ? ev : NSA * ev;
        }
        p_sh[wid][it][lane] = e;
    }
    __builtin_amdgcn_wave_barrier();

    // ---- group-parallel softmax over own node's 64 slots ----
    float4 ev4 = *(const float4*)&prow[d * 4];
    float m = fmaxf(fmaxf(ev4.x, ev4.y), fmaxf(ev4.z, ev4.w));
    #pragma unroll
    for (int off = 8; off >= 1; off >>= 1) m = fmaxf(m, __shfl_xor(m, off));
    float4 pv;
    pv.x = __expf(ev4.x - m);          // tail e=-1e30 -> 0
    pv.y = __expf(ev4.y - m);
    pv.z = __expf(ev4.z - m);
    pv.w = __expf(ev4.w - m);
    *(float4*)&prow[d * 4] = pv;
    float lsum = pv.x + pv.y + pv.z + pv.w;
    #pragma unroll
    for (int off = 8; off >= 1; off >>= 1) lsum += __shfl_xor(lsum, off);
    __builtin_amdgcn_wave_barrier();   // p values valid group-wide

    // ---- phase 2: consume chunk, reload in place ----
    float4 a0 = {0, 0, 0, 0}, a1 = {0, 0, 0, 0};
    int c = 0;
    while (true) {
        EAT(c);
        if (++c >= nch) break;
        LDCH(c);
    }

    float inv = 1.f / (lsum + EPS);
    float4 o0, o1;
    o0.x = a0.x * inv; o0.y = a0.y * inv; o0.z = a0.z * inv; o0.w = a0.w * inv;
    o1.x = a1.x * inv; o1.y = a1.y * inv; o1.z = a1.z * inv; o1.w = a1.w * inv;
    if (apply_lrelu) {
        o0.x = (o0.x > 0.f) ? o0.x : NSB * o0.x;
        o0.y = (o0.y > 0.f) ? o0.y : NSB * o0.y;
        o0.z = (o0.z > 0.f) ? o0.z : NSB * o0.z;
        o0.w = (o0.w > 0.f) ? o0.w : NSB * o0.w;
        o1.x = (o1.x > 0.f) ? o1.x : NSB * o1.x;
        o1.y = (o1.y > 0.f) ? o1.y : NSB * o1.y;
        o1.z = (o1.z > 0.f) ? o1.z : NSB * o1.z;
        o1.w = (o1.w > 0.f) ? o1.w : NSB * o1.w;
    }
    __half2 hh[4];
    hh[0] = __floats2half2_rn(o0.x, o0.y);
    hh[1] = __floats2half2_rn(o0.z, o0.w);
    hh[2] = __floats2half2_rn(o1.x, o1.y);
    hh[3] = __floats2half2_rn(o1.z, o1.w);
    *(float4*)&ytile[g * 4 + wid][d * 8] = *(float4*)hh;
}

// ---------------- FUSED agg+gemm: 16 nodes/block; agg -> LDS -> 16x128 MFMA ----------
__global__ __launch_bounds__(256, 6) void agg_gemm_kernel(
        const __half* __restrict__ H_in, const float* __restrict__ as_in,
        const float* __restrict__ ad_in, const unsigned int* __restrict__ cnt,
        const unsigned short* __restrict__ slots,
        const __half* __restrict__ W16, const float* __restrict__ a_src,
        const float* __restrict__ a_dst, __half* __restrict__ H_out,
        float* __restrict__ as_out, float* __restrict__ ad_out, int apply_lrelu) {
    __shared__ float  p_sh[4][4][64];
    __shared__ int    s_sh[4][4][64];
    __shared__ __half ytile[16][136];   // agg rows (A), later reused for C
    int t = threadIdx.x;
    int wid = t >> 6, lane = t & 63;
    int row0 = blockIdx.x * 16;

    agg_batch4(row0, wid, lane, H_in, as_in, ad_in, cnt, slots, p_sh, s_sh, ytile,
               apply_lrelu);
    __syncthreads();   // ytile complete

    int quad = lane >> 4, mrow = lane & 15;
    half8 afrag[4];
    #pragma unroll
    for (int kc = 0; kc < 4; ++kc)
        afrag[kc] = *(const half8*)&ytile[mrow][kc * 32 + quad * 8];
    __syncthreads();   // all A reads done; ytile reusable for C

    floatx4 acc[2] = {};
    #pragma unroll
    for (int cc = 0; cc < 2; ++cc) {
        int ct = wid * 2 + cc;
        #pragma unroll
        for (int kc = 0; kc < 4; ++kc) {
            half8 b = *(const half8*)&W16[(size_t)(ct * 16 + mrow) * DD + kc * 32 + quad * 8];
            acc[cc] = __builtin_amdgcn_mfma_f32_16x16x32_f16(afrag[kc], b, acc[cc], 0, 0, 0);
        }
    }
    #pragma unroll
    for (int cc = 0; cc < 2; ++cc) {
        int ct = wid * 2 + cc;
        #pragma unroll
        for (int reg = 0; reg < 4; ++reg)
            ytile[quad * 4 + reg][ct * 16 + mrow] = __float2half(acc[cc][reg]);
    }
    __syncthreads();

    int row = t >> 4, cg = t & 15;
    int gr = row0 + row;
    float4 raw = *(const float4*)&ytile[row][cg * 8];
    const __half2* q = (const __half2*)&raw;
    float2 c01 = __half22float2(q[0]);
    float2 c23 = __half22float2(q[1]);
    float2 c45 = __half22float2(q[2]);
    float2 c67 = __half22float2(q[3]);
    float hv[8] = {c01.x, c01.y, c23.x, c23.y, c45.x, c45.y, c67.x, c67.y};
    float ps = 0.f, pd = 0.f;
    #pragma unroll
    for (int c = 0; c < 8; ++c) {
        ps += hv[c] * a_src[cg * 8 + c];
        pd += hv[c] * a_dst[cg * 8 + c];
    }
    #pragma unroll
    for (int off = 8; off >= 1; off >>= 1) {
        ps += __shfl_xor(ps, off);
        pd += __shfl_xor(pd, off);
    }
    if (cg == 0) { as_out[gr] = ps; ad_out[gr] = pd; }
    *(float4*)&H_out[(size_t)gr * DD + cg * 8] = raw;
}

// ---------------- FUSED layer-2 agg + global_add_pool: 16 nodes/block ---------------
__global__ __launch_bounds__(256, 6) void agg_pool_kernel(
        const __half* __restrict__ H_in, const float* __restrict__ as_in,
        const float* __restrict__ ad_in, const unsigned int* __restrict__ cnt,
        const unsigned short* __restrict__ slots,
        const int* __restrict__ batch, float* __restrict__ out) {
    __shared__ float  p_sh[4][4][64];
    __shared__ int    s_sh[4][4][64];
    __shared__ __half ytile[16][136];
    int t = threadIdx.x;
    int wid = t >> 6, lane = t & 63;
    int row0 = blockIdx.x * 16;

    agg_batch4(row0, wid, lane, H_in, as_in, ad_in, cnt, slots, p_sh, s_sh, ytile, 0);
    __syncthreads();   // ytile complete

    // pool phase: rh = row half (0: rows 0-7, 1: rows 8-15), d = dim 0..127
    int rh = t >> 7;
    int d  = t & 127;
    int r0 = rh * 8;
    float acc = 0.f;
    int g = batch[row0 + r0];
    #pragma unroll
    for (int r = 0; r < 8; ++r) {
        int n = row0 + r0 + r;
        int gn = batch[n];
        if (gn != g) {
            atomicAdd(&out[(size_t)g * DD + d], acc);
            acc = 0.f;
            g = gn;
        }
        acc += __half2float(ytile[r0 + r][d]);
    }
    atomicAdd(&out[(size_t)g * DD + d], acc);
}

extern "C" void kernel_launch(void* const* d_in, const int* in_sizes, int n_in,
                              void* d_out, int out_size, void* d_ws, size_t ws_size,
                              hipStream_t stream) {
    const float* x      = (const float*)d_in[0];
    const int*   ei     = (const int*)d_in[1];
    const int*   batch  = (const int*)d_in[2];
    const int*   src    = ei;
    const int*   dst    = ei + NE;
    float* out = (float*)d_out;

    size_t off = 0;
    auto carve = [&](size_t bytes) {
        void* p = (char*)d_ws + off;
        off += (bytes + 255) & ~(size_t)255;
        return p;
    };
    __half* h16a  = (__half*)carve((size_t)NN * DD * 2);      // ping
    __half* h16b  = (__half*)carve((size_t)NN * DD * 2);      // pong
    float*  as_a  = (float*)carve((size_t)NN * 4);
    float*  ad_a  = (float*)carve((size_t)NN * 4);
    float*  as_b  = (float*)carve((size_t)NN * 4);
    float*  ad_b  = (float*)carve((size_t)NN * 4);
    unsigned int*   cnt   = (unsigned int*)carve((size_t)NN * 4);        // dense
    unsigned short* slots = (unsigned short*)carve((size_t)NN * 64 * 2); // store-only
    __half* w16   = (__half*)carve((size_t)3 * DD * DD * 2);

    const int gemm_blocks = (NN + BM - 1) / BM;      // 782
    const int fat_blocks  = gemm_blocks * 2;         // 1564: even=gemm, odd=scatter
    const int fuse_blocks = NN / 16;                 // 3125
    const int init_blocks = (NG * DD + 255) / 256;   // 256 (covers NN and 3*DD*DD)

    const float* W0  = (const float*)d_in[3];
    const float* av0 = (const float*)d_in[4];
    const float* ad0 = (const float*)d_in[5];
    const float* av1 = (const float*)d_in[7];
    const float* ad1 = (const float*)d_in[8];
    const float* av2 = (const float*)d_in[10];
    const float* ad2 = (const float*)d_in[11];

    // ---- init + (gemm0-MFMA || scatter, interleaved) ----
    init_kernel<<<init_blocks, 256, 0, stream>>>(cnt, out, W0,
                                                 (const float*)d_in[6],
                                                 (const float*)d_in[9], w16);
    fat_kernel<<<fat_blocks, 256, 0, stream>>>(
        x, w16, av0, ad0, h16a, as_a, ad_a, src, dst, cnt, slots);

    // ---- fused agg0+gemm1 (hA->hB), fused agg1+lrelu+gemm2 (hB->hA) ----
    agg_gemm_kernel<<<fuse_blocks, 256, 0, stream>>>(
        h16a, as_a, ad_a, cnt, slots, w16 + (size_t)1 * DD * DD, av1, ad1,
        h16b, as_b, ad_b, 0);
    agg_gemm_kernel<<<fuse_blocks, 256, 0, stream>>>(
        h16b, as_b, ad_b, cnt, slots, w16 + (size_t)2 * DD * DD, av2, ad2,
        h16a, as_a, ad_a, 1);

    // ---- fused layer-2 agg + pool ----
    agg_pool_kernel<<<fuse_blocks, 256, 0, stream>>>(h16a, as_a, ad_a, cnt, slots,
                                                     batch, out);
}